// Round 8
// baseline (291.298 us; speedup 1.0000x reference)
//
#include <hip/hip_runtime.h>

typedef __attribute__((ext_vector_type(8))) short bf16x8;
typedef __attribute__((ext_vector_type(4))) float f32x4;

__device__ __forceinline__ unsigned short f2b(float f) {
    unsigned u = __builtin_bit_cast(unsigned, f);
    u += 0x7fffu + ((u >> 16) & 1u);
    return (unsigned short)(u >> 16);
}

#define GLD_LDS(gp, lp) __builtin_amdgcn_global_load_lds( \
    (const __attribute__((address_space(1))) void*)(gp),  \
    (__attribute__((address_space(3))) void*)(lp), 16, 0, 0)

#define MFMA16(a, b, cacc) __builtin_amdgcn_mfma_f32_16x16x32_bf16(a, b, cacc, 0, 0, 0)

#define QSCL 0.18033688011112042f  // (1/8) * log2(e) folded into Wq/bq

// ---------------- fused fp32 -> bf16 convert of x + 4 weights ----------------
__global__ __launch_bounds__(256) void cvt_all(const float* __restrict__ x,
        const float* __restrict__ w0, const float* __restrict__ w1,
        const float* __restrict__ w2, const float* __restrict__ w3,
        short* xb, short* o0, short* o1, short* o2, short* o3) {
    int i = blockIdx.x * 256 + threadIdx.x;
    const float* in; short* out; int off; float scl = 1.0f;
    if (i < (1 << 20)) { in = x; out = xb; off = i; }
    else {
        int j = (i - (1 << 20)) >> 18;
        off = (i - (1 << 20)) & ((1 << 18) - 1);
        switch (j) {
            case 0: in = w0; out = o0; scl = QSCL; break;
            case 1: in = w1; out = o1; break;
            case 2: in = w2; out = o2; break;
            default: in = w3; out = o3; break;
        }
    }
    float4 v = reinterpret_cast<const float4*>(in)[off];
    short4 o;
    o.x = (short)f2b(v.x * scl); o.y = (short)f2b(v.y * scl);
    o.z = (short)f2b(v.z * scl); o.w = (short)f2b(v.w * scl);
    reinterpret_cast<short4*>(out)[off] = o;
}

// ---------------- QKV GEMM, direct-from-global (no LDS, no barriers) ----------------
// grid (16, 32, 3): n-tile, m-tile, mat. Block = 128 thr (2 waves); wave w computes
// rows [by*128 + w*64, +64) x cols [bx*64, +64) via 4x4 16x16x32 MFMAs.
// Fragment loads: lanes (c, g=0..3) read 4 contiguous 16B chunks of one 64B line
// (full sector utilization); A-panels/W are L2/L3-resident -> latency is L2-class.
__global__ __launch_bounds__(128) void qkv_gemm(const short* __restrict__ A,
        const short* __restrict__ Wq, const short* __restrict__ Wk, const short* __restrict__ Wv,
        const float* __restrict__ bq, const float* __restrict__ bk, const float* __restrict__ bv,
        short* __restrict__ Oq, short* __restrict__ Ok, short* __restrict__ Ovt) {
    constexpr int Kd = 1024, N = 1024, S = 2048;
    const int mat = blockIdx.z;
    const short* Bm = (mat == 0) ? Wq : (mat == 1 ? Wk : Wv);
    const float* bias = (mat == 0) ? bq : (mat == 1 ? bk : bv);
    const float bscl = (mat == 0) ? QSCL : 1.0f;
    const int n0 = blockIdx.x * 64;
    const int w = threadIdx.x >> 6, lane = threadIdx.x & 63;
    const int m0 = blockIdx.y * 128 + w * 64;
    const int c = lane & 15, g = lane >> 4;

    const short* pA = A + (size_t)(m0 + c) * Kd + g * 8;
    const short* pB = Bm + (size_t)(n0 + c) * Kd + g * 8;

    f32x4 acc[4][4] = {};

#pragma unroll 2
    for (int kk = 0; kk < 32; ++kk) {
        bf16x8 af[4], bfr[4];
#pragma unroll
        for (int mi = 0; mi < 4; ++mi)
            af[mi] = *(const bf16x8*)(pA + mi * 16 * Kd + kk * 32);
#pragma unroll
        for (int ni = 0; ni < 4; ++ni)
            bfr[ni] = *(const bf16x8*)(pB + ni * 16 * Kd + kk * 32);
#pragma unroll
        for (int mi = 0; mi < 4; ++mi)
#pragma unroll
            for (int ni = 0; ni < 4; ++ni)
                acc[mi][ni] = MFMA16(af[mi], bfr[ni], acc[mi][ni]);
    }

    if (mat < 2) {
        short* Cb = (mat == 0) ? Oq : Ok;
#pragma unroll
        for (int mi = 0; mi < 4; ++mi)
#pragma unroll
            for (int ni = 0; ni < 4; ++ni) {
                int col = n0 + ni * 16 + c;
                float bvv = bias[col] * bscl;
#pragma unroll
                for (int r = 0; r < 4; ++r) {
                    int row = m0 + mi * 16 + g * 4 + r;
                    Cb[(size_t)row * N + col] = (short)f2b(acc[mi][ni][r] + bvv);
                }
            }
    } else {
        // V: write transposed to Vt[bh=b*16+h][hd][s], s-contiguous short4
#pragma unroll
        for (int mi = 0; mi < 4; ++mi)
#pragma unroll
            for (int ni = 0; ni < 4; ++ni) {
                int col = n0 + ni * 16 + c;  // d index
                int h = col >> 6, hd = col & 63;
                float bvv = bias[col];
                int row0 = m0 + mi * 16 + g * 4;  // 4 consecutive s
                int b = row0 >> 11, s = row0 & 2047;
                short4 pk;
                pk.x = (short)f2b(acc[mi][ni][0] + bvv);
                pk.y = (short)f2b(acc[mi][ni][1] + bvv);
                pk.z = (short)f2b(acc[mi][ni][2] + bvv);
                pk.w = (short)f2b(acc[mi][ni][3] + bvv);
                *(short4*)(Ovt + ((size_t)((b * 16 + h) * 64 + hd)) * S + s) = pk;
            }
    }
}

// ---------------- out-proj GEMM, direct-from-global, fp32 out ----------------
// grid (16, 32), block 128 (2 waves); wave: 64x64 tile.
__global__ __launch_bounds__(128) void out_gemm(const short* __restrict__ A,
                                                const short* __restrict__ Bm,
                                                const float* __restrict__ bias,
                                                float* __restrict__ C) {
    constexpr int Kd = 1024, N = 1024;
    const int n0 = blockIdx.x * 64;
    const int w = threadIdx.x >> 6, lane = threadIdx.x & 63;
    const int m0 = blockIdx.y * 128 + w * 64;
    const int c = lane & 15, g = lane >> 4;

    const short* pA = A + (size_t)(m0 + c) * Kd + g * 8;
    const short* pB = Bm + (size_t)(n0 + c) * Kd + g * 8;

    f32x4 acc[4][4] = {};

#pragma unroll 2
    for (int kk = 0; kk < 32; ++kk) {
        bf16x8 af[4], bfr[4];
#pragma unroll
        for (int mi = 0; mi < 4; ++mi)
            af[mi] = *(const bf16x8*)(pA + mi * 16 * Kd + kk * 32);
#pragma unroll
        for (int ni = 0; ni < 4; ++ni)
            bfr[ni] = *(const bf16x8*)(pB + ni * 16 * Kd + kk * 32);
#pragma unroll
        for (int mi = 0; mi < 4; ++mi)
#pragma unroll
            for (int ni = 0; ni < 4; ++ni)
                acc[mi][ni] = MFMA16(af[mi], bfr[ni], acc[mi][ni]);
    }

#pragma unroll
    for (int mi = 0; mi < 4; ++mi)
#pragma unroll
        for (int ni = 0; ni < 4; ++ni) {
            int col = n0 + ni * 16 + c;
            float bvv = bias[col];
#pragma unroll
            for (int r = 0; r < 4; ++r) {
                int row = m0 + mi * 16 + g * 4 + r;
                C[(size_t)row * N + col] = acc[mi][ni][r] + bvv;
            }
        }
}

// ---------------- flash attention, fixed-max softmax, deferred l ----------------
// (unchanged — isolating the GEMM changes)
__global__ __launch_bounds__(256) void attn_kernel(const short* Q,
                                                   const short* __restrict__ Kg,
                                                   const short* __restrict__ Vt,
                                                   short* O) {
    constexpr int S = 2048, D = 1024;
    constexpr float M2 = 16.0f;
    __shared__ short Ks[64 * 64];
    __shared__ short Vs[64 * 64];
    __shared__ short Pl[4][16 * 64];
    const int id = blockIdx.x;
    const int bh = id & 31, b = bh >> 4, h = bh & 15;
    const int qtile = 31 - (id >> 5);
    const int t = threadIdx.x;
    const int w = t >> 6, lane = t & 63;
    const int c = lane & 15, g = lane >> 4;
    const int q0 = qtile * 64 + w * 16;

    const short* Qb = Q + (size_t)b * S * D + h * 64;
    const short* Kp = Kg + (size_t)b * S * D + h * 64;
    const short* Vp = Vt + (size_t)bh * 64 * S;

    bf16x8 aq0 = *(const bf16x8*)(Qb + (size_t)(q0 + c) * D + g * 8);
    bf16x8 aq1 = *(const bf16x8*)(Qb + (size_t)(q0 + c) * D + 32 + g * 8);

    f32x4 o[4] = {};
    float l_part[4] = {0.f, 0.f, 0.f, 0.f};

    const int ktmax = qtile + 1;
    for (int kt = 0; kt < ktmax; ++kt) {
        const int k0 = kt * 64;
#pragma unroll
        for (int cc = 0; cc < 2; ++cc) {
            int row = cc * 32 + (t >> 3);
            int colb = ((t & 7) * 16) ^ ((row & 7) << 4);
            GLD_LDS(Kp + (size_t)(k0 + row) * D + (colb >> 1), Ks + cc * 2048 + t * 8);
            GLD_LDS(Vp + (size_t)row * S + k0 + (colb >> 1), Vs + cc * 2048 + t * 8);
        }
        __syncthreads();

        f32x4 sc[4];
#pragma unroll
        for (int nt = 0; nt < 4; ++nt) {
            int row = nt * 16 + c;
            int sw = (row & 7) << 4;
            const char* rb = (const char*)Ks + row * 128;
            bf16x8 bk0 = *(const bf16x8*)(rb + ((g * 16) ^ sw));
            bf16x8 bk1 = *(const bf16x8*)(rb + ((64 + g * 16) ^ sw));
            f32x4 z = {};
            z = MFMA16(aq0, bk0, z);
            z = MFMA16(aq1, bk1, z);
            sc[nt] = z;
        }
        if (kt == ktmax - 1) {
#pragma unroll
            for (int nt = 0; nt < 4; ++nt)
#pragma unroll
                for (int r = 0; r < 4; ++r) {
                    int key = k0 + nt * 16 + c;
                    int qr = q0 + g * 4 + r;
                    if (key > qr) sc[nt][r] = -3e38f;
                }
        }
        char* pw = (char*)&Pl[w][0];
#pragma unroll
        for (int nt = 0; nt < 4; ++nt)
#pragma unroll
            for (int r = 0; r < 4; ++r) {
                float p = __builtin_exp2f(sc[nt][r] - M2);
                l_part[r] += p;
                int prow = g * 4 + r;
                int pb = ((nt * 16 + c) * 2) ^ ((prow & 7) << 4);
                *(short*)(pw + prow * 128 + pb) = (short)f2b(p);
            }
        asm volatile("" ::: "memory");
#pragma unroll
        for (int half = 0; half < 2; ++half) {
            bf16x8 pa = *(const bf16x8*)(pw + c * 128 + ((half * 64 + g * 16) ^ ((c & 7) << 4)));
#pragma unroll
            for (int n2 = 0; n2 < 4; ++n2) {
                int vrow = n2 * 16 + c;
                bf16x8 bv = *(const bf16x8*)((const char*)Vs + vrow * 128 +
                                             ((half * 64 + g * 16) ^ ((vrow & 7) << 4)));
                o[n2] = MFMA16(pa, bv, o[n2]);
            }
        }
        __syncthreads();
    }

#pragma unroll
    for (int d = 1; d < 16; d <<= 1)
#pragma unroll
        for (int r = 0; r < 4; ++r) l_part[r] += __shfl_xor(l_part[r], d);

    short* Ob = O + (size_t)b * S * D + h * 64;
#pragma unroll
    for (int r = 0; r < 4; ++r) {
        float inv = 1.0f / l_part[r];
        int row = q0 + g * 4 + r;
#pragma unroll
        for (int n2 = 0; n2 < 4; ++n2)
            Ob[(size_t)row * D + n2 * 16 + c] = (short)f2b(o[n2][r] * inv);
    }
}

extern "C" void kernel_launch(void* const* d_in, const int* in_sizes, int n_in,
                              void* d_out, int out_size, void* d_ws, size_t ws_size,
                              hipStream_t stream) {
    const float* x  = (const float*)d_in[0];
    const float* wq = (const float*)d_in[1];
    const float* bq = (const float*)d_in[2];
    const float* wk = (const float*)d_in[3];
    const float* bk = (const float*)d_in[4];
    const float* wv = (const float*)d_in[5];
    const float* bv = (const float*)d_in[6];
    const float* wo = (const float*)d_in[7];
    const float* bo = (const float*)d_in[8];
    float* out = (float*)d_out;

    char* ws = (char*)d_ws;
    const size_t SZ_X = (size_t)4096 * 1024 * 2;  // 8 MB
    const size_t SZ_W = (size_t)1024 * 1024 * 2;  // 2 MB
    short* xb  = (short*)(ws);
    short* wqb = (short*)(ws + SZ_X);
    short* wkb = (short*)(ws + SZ_X + SZ_W);
    short* wvb = (short*)(ws + SZ_X + 2 * SZ_W);
    short* wob = (short*)(ws + SZ_X + 3 * SZ_W);
    short* Qb  = (short*)(ws + SZ_X + 4 * SZ_W);   // also attn output (safe alias)
    short* Kbuf= (short*)(ws + 2 * SZ_X + 4 * SZ_W);
    short* Vtb = (short*)(ws + 3 * SZ_X + 4 * SZ_W);  // V in [bh][hd][s]
    short* Ab  = Qb;

    cvt_all<<<8192, 256, 0, stream>>>(x, wq, wk, wv, wo, xb, wqb, wkb, wvb, wob);

    qkv_gemm<<<dim3(16, 32, 3), 128, 0, stream>>>(xb, wqb, wkb, wvb, bq, bk, bv, Qb, Kbuf, Vtb);

    attn_kernel<<<1024, 256, 0, stream>>>(Qb, Kbuf, Vtb, Ab);

    out_gemm<<<dim3(16, 32), 128, 0, stream>>>(Ab, wob, bo, out);
}

// Round 9
// 195.235 us; speedup vs baseline: 1.4920x; 1.4920x over previous
//
#include <hip/hip_runtime.h>

typedef __attribute__((ext_vector_type(8))) short bf16x8;
typedef __attribute__((ext_vector_type(4))) float f32x4;

__device__ __forceinline__ unsigned short f2b(float f) {
    unsigned u = __builtin_bit_cast(unsigned, f);
    u += 0x7fffu + ((u >> 16) & 1u);
    return (unsigned short)(u >> 16);
}

#define GLD_LDS(gp, lp) __builtin_amdgcn_global_load_lds( \
    (const __attribute__((address_space(1))) void*)(gp),  \
    (__attribute__((address_space(3))) void*)(lp), 16, 0, 0)

#define MFMA16(a, b, cacc) __builtin_amdgcn_mfma_f32_16x16x32_bf16(a, b, cacc, 0, 0, 0)

#define QSCL 0.18033688011112042f  // (1/8) * log2(e) folded into Wq/bq

// ---------------- fused fp32 -> bf16 convert of x + 4 weights ----------------
__global__ __launch_bounds__(256) void cvt_all(const float* __restrict__ x,
        const float* __restrict__ w0, const float* __restrict__ w1,
        const float* __restrict__ w2, const float* __restrict__ w3,
        short* xb, short* o0, short* o1, short* o2, short* o3) {
    int i = blockIdx.x * 256 + threadIdx.x;
    const float* in; short* out; int off; float scl = 1.0f;
    if (i < (1 << 20)) { in = x; out = xb; off = i; }
    else {
        int j = (i - (1 << 20)) >> 18;
        off = (i - (1 << 20)) & ((1 << 18) - 1);
        switch (j) {
            case 0: in = w0; out = o0; scl = QSCL; break;
            case 1: in = w1; out = o1; break;
            case 2: in = w2; out = o2; break;
            default: in = w3; out = o3; break;
        }
    }
    float4 v = reinterpret_cast<const float4*>(in)[off];
    short4 o;
    o.x = (short)f2b(v.x * scl); o.y = (short)f2b(v.y * scl);
    o.z = (short)f2b(v.z * scl); o.w = (short)f2b(v.w * scl);
    reinterpret_cast<short4*>(out)[off] = o;
}

// ---------------- fused QKV GEMM: 256x128 tile, BK=64, counted-vmcnt depth-2 ----------------
// grid (24, 16), 512 thr (8 waves, 4M x 2N; wave = 64x64 out). C[4096, 3072] view:
// nt>>3 = mat (0=Q,1=K,2=V). 3 LDS buffers x (A 256x64 + B 128x64) bf16 = 144 KB dynamic.
// Pipeline: tile u staged (6 gld_lds/thread) at iter u-2 into buf[u%3].
// Per iter: vmcnt(6) [tail: 0] -> s_barrier -> stage(t+2) -> swizzled ds_read -> MFMA.
// Race-free: WAR: stage target last read in iter t-1, closed by this iter's barrier;
// RAW: vmcnt(6) leaves only tile t+1 in flight => tile t landed; barrier publishes.
__global__ __launch_bounds__(512) void qkv_gemm(const short* __restrict__ A,
        const short* __restrict__ Wq, const short* __restrict__ Wk, const short* __restrict__ Wv,
        const float* __restrict__ bq, const float* __restrict__ bk, const float* __restrict__ bv,
        short* __restrict__ Oq, short* __restrict__ Ok, short* __restrict__ Ovt) {
    constexpr int Kd = 1024, S = 2048;
    constexpr int ABUF = 256 * 64;          // shorts
    constexpr int BBUF = 128 * 64;
    constexpr int TBUF = ABUF + BBUF;       // 24576 shorts = 48 KB
    extern __shared__ short lds[];          // 3 * TBUF
    const int nt = blockIdx.x;
    const int mat = nt >> 3;
    const int n0m = (nt & 7) * 128;         // col within mat
    const int m0 = blockIdx.y * 256;
    const short* Bm = (mat == 0) ? Wq : (mat == 1 ? Wk : Wv);
    const float* bias = (mat == 0) ? bq : (mat == 1 ? bk : bv);
    const float bscl = (mat == 0) ? QSCL : 1.0f;
    const int t = threadIdx.x;
    const int w = t >> 6, lane = t & 63;
    const int wm = w >> 1, wn = w & 1;
    const int c = lane & 15, g = lane >> 4;

    f32x4 acc[4][4] = {};

    auto stage = [&](int buf, int k0) {
        short* La = lds + buf * TBUF;
        short* Lb = La + ABUF;
#pragma unroll
        for (int cc = 0; cc < 4; ++cc) {            // A: 256x64, 2048 chunks of 16B
            int chunk = cc * 512 + t;
            int row = chunk >> 3, s = chunk & 7;
            int colb = (s * 16) ^ ((row & 7) << 4); // pre-swizzled source (m173)
            GLD_LDS(A + (size_t)(m0 + row) * Kd + k0 + (colb >> 1), La + chunk * 8);
        }
#pragma unroll
        for (int cc = 0; cc < 2; ++cc) {            // B: 128x64, 1024 chunks
            int chunk = cc * 512 + t;
            int row = chunk >> 3, s = chunk & 7;
            int colb = (s * 16) ^ ((row & 7) << 4);
            GLD_LDS(Bm + (size_t)(n0m + row) * Kd + k0 + (colb >> 1), Lb + chunk * 8);
        }
    };

    stage(0, 0);
    stage(1, 64);

    int cur = 0;
#pragma unroll 1
    for (int kt = 0; kt < 16; ++kt) {
        if (kt < 15) asm volatile("s_waitcnt vmcnt(6)" ::: "memory");
        else         asm volatile("s_waitcnt vmcnt(0)" ::: "memory");
        __builtin_amdgcn_sched_barrier(0);
        __builtin_amdgcn_s_barrier();
        __builtin_amdgcn_sched_barrier(0);
        if (kt + 2 < 16) {
            int nbuf = cur + 2; if (nbuf >= 3) nbuf -= 3;
            stage(nbuf, (kt + 2) * 64);
        }
        const short* La = lds + cur * TBUF;
        const short* Lb = La + ABUF;
#pragma unroll
        for (int kk = 0; kk < 2; ++kk) {
            bf16x8 af[4], bfr[4];
#pragma unroll
            for (int mi = 0; mi < 4; ++mi) {
                int row = wm * 64 + mi * 16 + c;
                af[mi] = *(const bf16x8*)((const char*)La + row * 128 +
                                          ((kk * 64 + g * 16) ^ ((row & 7) << 4)));
            }
#pragma unroll
            for (int ni = 0; ni < 4; ++ni) {
                int row = wn * 64 + ni * 16 + c;
                bfr[ni] = *(const bf16x8*)((const char*)Lb + row * 128 +
                                           ((kk * 64 + g * 16) ^ ((row & 7) << 4)));
            }
            __builtin_amdgcn_s_setprio(1);
#pragma unroll
            for (int mi = 0; mi < 4; ++mi)
#pragma unroll
                for (int ni = 0; ni < 4; ++ni)
                    acc[mi][ni] = MFMA16(af[mi], bfr[ni], acc[mi][ni]);
            __builtin_amdgcn_s_setprio(0);
        }
        ++cur; if (cur == 3) cur = 0;
    }

    if (mat < 2) {
        short* Cb = (mat == 0) ? Oq : Ok;
#pragma unroll
        for (int mi = 0; mi < 4; ++mi)
#pragma unroll
            for (int ni = 0; ni < 4; ++ni) {
                int col = n0m + wn * 64 + ni * 16 + c;
                float bvv = bias[col] * bscl;
#pragma unroll
                for (int r = 0; r < 4; ++r) {
                    int row = m0 + wm * 64 + mi * 16 + g * 4 + r;
                    Cb[(size_t)row * 1024 + col] = (short)f2b(acc[mi][ni][r] + bvv);
                }
            }
    } else {
        // V: write transposed to Vt[bh=b*16+h][hd][s], s-contiguous short4
#pragma unroll
        for (int mi = 0; mi < 4; ++mi)
#pragma unroll
            for (int ni = 0; ni < 4; ++ni) {
                int col = n0m + wn * 64 + ni * 16 + c;  // d index
                int h = col >> 6, hd = col & 63;
                float bvv = bias[col];
                int row0 = m0 + wm * 64 + mi * 16 + g * 4;  // 4 consecutive s
                int b = row0 >> 11, s = row0 & 2047;
                short4 pk;
                pk.x = (short)f2b(acc[mi][ni][0] + bvv);
                pk.y = (short)f2b(acc[mi][ni][1] + bvv);
                pk.z = (short)f2b(acc[mi][ni][2] + bvv);
                pk.w = (short)f2b(acc[mi][ni][3] + bvv);
                *(short4*)(Ovt + ((size_t)((b * 16 + h) * 64 + hd)) * S + s) = pk;
            }
    }
}

// ---------------- out-proj GEMM: 64x128 tile, BK=32 dbuf + swizzle, fp32 out ----------------
__global__ __launch_bounds__(256) void out_gemm(const short* __restrict__ A,
                                                const short* __restrict__ Bm,
                                                const float* __restrict__ bias,
                                                float* __restrict__ C) {
    constexpr int Kd = 1024, N = 1024;
    __shared__ short As[2][64 * 32];
    __shared__ short Bs[2][128 * 32];
    const int n0 = blockIdx.x * 128, m0 = blockIdx.y * 64;
    const int t = threadIdx.x;
    const int w = t >> 6, lane = t & 63;
    const int wm = w >> 1, wn = w & 1;
    const int c = lane & 15, g = lane >> 4;

    f32x4 acc[2][4] = {};

    auto stage = [&](int buf, int k0) {
        {
            int e = t * 8;
            int row = e >> 5;
            int col = (e & 31) ^ (((row >> 1) & 3) << 3);
            GLD_LDS(A + (size_t)(m0 + row) * Kd + k0 + col, &As[buf][e]);
        }
#pragma unroll
        for (int cc = 0; cc < 2; ++cc) {
            int e = (cc * 256 + t) * 8;
            int row = e >> 5;
            int col = (e & 31) ^ (((row >> 1) & 3) << 3);
            GLD_LDS(Bm + (size_t)(n0 + row) * Kd + k0 + col, &Bs[buf][e]);
        }
    };

    stage(0, 0);
    __syncthreads();
    int cur = 0;
    for (int ks = 0; ks < 32; ++ks) {
        if (ks + 1 < 32) stage(cur ^ 1, (ks + 1) * 32);
        const short* Ab_ = As[cur];
        const short* Bb_ = Bs[cur];
        bf16x8 af[2], bfr[4];
#pragma unroll
        for (int mi = 0; mi < 2; ++mi) {
            int ar = wm * 32 + mi * 16 + c;
            af[mi] = *(const bf16x8*)(Ab_ + ar * 32 + ((g * 8) ^ (((ar >> 1) & 3) << 3)));
        }
#pragma unroll
        for (int ni = 0; ni < 4; ++ni) {
            int br = wn * 64 + ni * 16 + c;
            bfr[ni] = *(const bf16x8*)(Bb_ + br * 32 + ((g * 8) ^ (((br >> 1) & 3) << 3)));
        }
#pragma unroll
        for (int mi = 0; mi < 2; ++mi)
#pragma unroll
            for (int ni = 0; ni < 4; ++ni)
                acc[mi][ni] = MFMA16(af[mi], bfr[ni], acc[mi][ni]);
        __syncthreads();
        cur ^= 1;
    }

#pragma unroll
    for (int mi = 0; mi < 2; ++mi)
#pragma unroll
        for (int ni = 0; ni < 4; ++ni) {
            int col = n0 + wn * 64 + ni * 16 + c;
            float bvv = bias[col];
#pragma unroll
            for (int r = 0; r < 4; ++r) {
                int row = m0 + wm * 32 + mi * 16 + g * 4 + r;
                C[(size_t)row * N + col] = acc[mi][ni][r] + bvv;
            }
        }
}

// ---------------- flash attention, fixed-max softmax, deferred l (unchanged) ----------------
__global__ __launch_bounds__(256) void attn_kernel(const short* Q,
                                                   const short* __restrict__ Kg,
                                                   const short* __restrict__ Vt,
                                                   short* O) {
    constexpr int S = 2048, D = 1024;
    constexpr float M2 = 16.0f;
    __shared__ short Ks[64 * 64];
    __shared__ short Vs[64 * 64];
    __shared__ short Pl[4][16 * 64];
    const int id = blockIdx.x;
    const int bh = id & 31, b = bh >> 4, h = bh & 15;
    const int qtile = 31 - (id >> 5);
    const int t = threadIdx.x;
    const int w = t >> 6, lane = t & 63;
    const int c = lane & 15, g = lane >> 4;
    const int q0 = qtile * 64 + w * 16;

    const short* Qb = Q + (size_t)b * S * D + h * 64;
    const short* Kp = Kg + (size_t)b * S * D + h * 64;
    const short* Vp = Vt + (size_t)bh * 64 * S;

    bf16x8 aq0 = *(const bf16x8*)(Qb + (size_t)(q0 + c) * D + g * 8);
    bf16x8 aq1 = *(const bf16x8*)(Qb + (size_t)(q0 + c) * D + 32 + g * 8);

    f32x4 o[4] = {};
    float l_part[4] = {0.f, 0.f, 0.f, 0.f};

    const int ktmax = qtile + 1;
    for (int kt = 0; kt < ktmax; ++kt) {
        const int k0 = kt * 64;
#pragma unroll
        for (int cc = 0; cc < 2; ++cc) {
            int row = cc * 32 + (t >> 3);
            int colb = ((t & 7) * 16) ^ ((row & 7) << 4);
            GLD_LDS(Kp + (size_t)(k0 + row) * D + (colb >> 1), Ks + cc * 2048 + t * 8);
            GLD_LDS(Vp + (size_t)row * S + k0 + (colb >> 1), Vs + cc * 2048 + t * 8);
        }
        __syncthreads();

        f32x4 sc[4];
#pragma unroll
        for (int nt = 0; nt < 4; ++nt) {
            int row = nt * 16 + c;
            int sw = (row & 7) << 4;
            const char* rb = (const char*)Ks + row * 128;
            bf16x8 bk0 = *(const bf16x8*)(rb + ((g * 16) ^ sw));
            bf16x8 bk1 = *(const bf16x8*)(rb + ((64 + g * 16) ^ sw));
            f32x4 z = {};
            z = MFMA16(aq0, bk0, z);
            z = MFMA16(aq1, bk1, z);
            sc[nt] = z;
        }
        if (kt == ktmax - 1) {
#pragma unroll
            for (int nt = 0; nt < 4; ++nt)
#pragma unroll
                for (int r = 0; r < 4; ++r) {
                    int key = k0 + nt * 16 + c;
                    int qr = q0 + g * 4 + r;
                    if (key > qr) sc[nt][r] = -3e38f;
                }
        }
        char* pw = (char*)&Pl[w][0];
#pragma unroll
        for (int nt = 0; nt < 4; ++nt)
#pragma unroll
            for (int r = 0; r < 4; ++r) {
                float p = __builtin_exp2f(sc[nt][r] - M2);
                l_part[r] += p;
                int prow = g * 4 + r;
                int pb = ((nt * 16 + c) * 2) ^ ((prow & 7) << 4);
                *(short*)(pw + prow * 128 + pb) = (short)f2b(p);
            }
        asm volatile("" ::: "memory");
#pragma unroll
        for (int half = 0; half < 2; ++half) {
            bf16x8 pa = *(const bf16x8*)(pw + c * 128 + ((half * 64 + g * 16) ^ ((c & 7) << 4)));
#pragma unroll
            for (int n2 = 0; n2 < 4; ++n2) {
                int vrow = n2 * 16 + c;
                bf16x8 bv = *(const bf16x8*)((const char*)Vs + vrow * 128 +
                                             ((half * 64 + g * 16) ^ ((vrow & 7) << 4)));
                o[n2] = MFMA16(pa, bv, o[n2]);
            }
        }
        __syncthreads();
    }

#pragma unroll
    for (int d = 1; d < 16; d <<= 1)
#pragma unroll
        for (int r = 0; r < 4; ++r) l_part[r] += __shfl_xor(l_part[r], d);

    short* Ob = O + (size_t)b * S * D + h * 64;
#pragma unroll
    for (int r = 0; r < 4; ++r) {
        float inv = 1.0f / l_part[r];
        int row = q0 + g * 4 + r;
#pragma unroll
        for (int n2 = 0; n2 < 4; ++n2)
            Ob[(size_t)row * D + n2 * 16 + c] = (short)f2b(o[n2][r] * inv);
    }
}

extern "C" void kernel_launch(void* const* d_in, const int* in_sizes, int n_in,
                              void* d_out, int out_size, void* d_ws, size_t ws_size,
                              hipStream_t stream) {
    const float* x  = (const float*)d_in[0];
    const float* wq = (const float*)d_in[1];
    const float* bq = (const float*)d_in[2];
    const float* wk = (const float*)d_in[3];
    const float* bk = (const float*)d_in[4];
    const float* wv = (const float*)d_in[5];
    const float* bv = (const float*)d_in[6];
    const float* wo = (const float*)d_in[7];
    const float* bo = (const float*)d_in[8];
    float* out = (float*)d_out;

    char* ws = (char*)d_ws;
    const size_t SZ_X = (size_t)4096 * 1024 * 2;  // 8 MB
    const size_t SZ_W = (size_t)1024 * 1024 * 2;  // 2 MB
    short* xb  = (short*)(ws);
    short* wqb = (short*)(ws + SZ_X);
    short* wkb = (short*)(ws + SZ_X + SZ_W);
    short* wvb = (short*)(ws + SZ_X + 2 * SZ_W);
    short* wob = (short*)(ws + SZ_X + 3 * SZ_W);
    short* Qb  = (short*)(ws + SZ_X + 4 * SZ_W);   // also attn output (safe alias)
    short* Kbuf= (short*)(ws + 2 * SZ_X + 4 * SZ_W);
    short* Vtb = (short*)(ws + 3 * SZ_X + 4 * SZ_W);  // V in [bh][hd][s]
    short* Ab  = Qb;

    static bool attr_set = false;
    if (!attr_set) {
        (void)hipFuncSetAttribute((const void*)qkv_gemm,
                                  hipFuncAttributeMaxDynamicSharedMemorySize, 147456);
        attr_set = true;
    }

    cvt_all<<<8192, 256, 0, stream>>>(x, wq, wk, wv, wo, xb, wqb, wkb, wvb, wob);

    qkv_gemm<<<dim3(24, 16), 512, 147456, stream>>>(xb, wqb, wkb, wvb, bq, bk, bv, Qb, Kbuf, Vtb);

    attn_kernel<<<1024, 256, 0, stream>>>(Qb, Kbuf, Vtb, Ab);

    out_gemm<<<dim3(8, 64), 256, 0, stream>>>(Ab, wob, bo, out);
}

// Round 10
// 191.566 us; speedup vs baseline: 1.5206x; 1.0192x over previous
//
#include <hip/hip_runtime.h>

typedef __attribute__((ext_vector_type(8))) short bf16x8;
typedef __attribute__((ext_vector_type(4))) float f32x4;

__device__ __forceinline__ unsigned short f2b(float f) {
    unsigned u = __builtin_bit_cast(unsigned, f);
    u += 0x7fffu + ((u >> 16) & 1u);
    return (unsigned short)(u >> 16);
}

#define GLD_LDS(gp, lp) __builtin_amdgcn_global_load_lds( \
    (const __attribute__((address_space(1))) void*)(gp),  \
    (__attribute__((address_space(3))) void*)(lp), 16, 0, 0)

#define MFMA16(a, b, cacc) __builtin_amdgcn_mfma_f32_16x16x32_bf16(a, b, cacc, 0, 0, 0)

#define QSCL 0.18033688011112042f  // (1/8) * log2(e) folded into Wq/bq

// ---------------- fused fp32 -> bf16 convert of x + 4 weights ----------------
__global__ __launch_bounds__(256) void cvt_all(const float* __restrict__ x,
        const float* __restrict__ w0, const float* __restrict__ w1,
        const float* __restrict__ w2, const float* __restrict__ w3,
        short* xb, short* o0, short* o1, short* o2, short* o3) {
    int i = blockIdx.x * 256 + threadIdx.x;
    const float* in; short* out; int off; float scl = 1.0f;
    if (i < (1 << 20)) { in = x; out = xb; off = i; }
    else {
        int j = (i - (1 << 20)) >> 18;
        off = (i - (1 << 20)) & ((1 << 18) - 1);
        switch (j) {
            case 0: in = w0; out = o0; scl = QSCL; break;
            case 1: in = w1; out = o1; break;
            case 2: in = w2; out = o2; break;
            default: in = w3; out = o3; break;
        }
    }
    float4 v = reinterpret_cast<const float4*>(in)[off];
    short4 o;
    o.x = (short)f2b(v.x * scl); o.y = (short)f2b(v.y * scl);
    o.z = (short)f2b(v.z * scl); o.w = (short)f2b(v.w * scl);
    reinterpret_cast<short4*>(out)[off] = o;
}

// ---------------- fused QKV GEMM: 128x128 tile, 4 waves, BK=32, 3-buf pipeline ----------------
// grid (24, 32): bx>>3 = mat (0=Q,1=K,2=V), bx&7 = n-tile; by = m-tile. 768 blocks = 3/CU
// resident (48 KB LDS each). Counted vmcnt(4): tile t+1's 4 loads stay in flight across the
// barrier. Swizzle: 64B LDS rows, slot ^= (row>>1)&3 (read xor = ((c>>1)&3)<<4, conflict-free).
__global__ __launch_bounds__(256, 3) void qkv_gemm(const short* __restrict__ A,
        const short* __restrict__ Wq, const short* __restrict__ Wk, const short* __restrict__ Wv,
        const float* __restrict__ bq, const float* __restrict__ bk, const float* __restrict__ bv,
        short* __restrict__ Oq, short* __restrict__ Ok, short* __restrict__ Ovt) {
    constexpr int Kd = 1024, S = 2048;
    __shared__ short La[3][128 * 32];
    __shared__ short Lb[3][128 * 32];
    const int bx = blockIdx.x;
    const int mat = bx >> 3;
    const int n0m = (bx & 7) * 128;
    const int m0 = blockIdx.y * 128;
    const short* Bm = (mat == 0) ? Wq : (mat == 1 ? Wk : Wv);
    const float* bias = (mat == 0) ? bq : (mat == 1 ? bk : bv);
    const float bscl = (mat == 0) ? QSCL : 1.0f;
    const int t = threadIdx.x;
    const int w = t >> 6, lane = t & 63;
    const int wm = w >> 1, wn = w & 1;
    const int c = lane & 15, g = lane >> 4;

    f32x4 acc[4][4] = {};

    auto stage = [&](int buf, int k0) {
#pragma unroll
        for (int cc = 0; cc < 2; ++cc) {
            int chunk = cc * 256 + t;
            int row = chunk >> 2, s = chunk & 3;
            int colb = (s * 16) ^ (((row >> 1) & 3) << 4);  // pre-swizzled source
            GLD_LDS(A + (size_t)(m0 + row) * Kd + k0 + (colb >> 1), &La[buf][chunk * 8]);
            GLD_LDS(Bm + (size_t)(n0m + row) * Kd + k0 + (colb >> 1), &Lb[buf][chunk * 8]);
        }
    };

    stage(0, 0);
    stage(1, 32);
    const int xr = ((c >> 1) & 3) << 4;

    int cur = 0;
#pragma unroll 1
    for (int ks = 0; ks < 32; ++ks) {
        if (ks < 31) asm volatile("s_waitcnt vmcnt(4)" ::: "memory");
        else         asm volatile("s_waitcnt vmcnt(0)" ::: "memory");
        __builtin_amdgcn_sched_barrier(0);
        __builtin_amdgcn_s_barrier();
        __builtin_amdgcn_sched_barrier(0);
        if (ks + 2 < 32) {
            int nb = cur + 2; if (nb >= 3) nb -= 3;
            stage(nb, (ks + 2) * 32);
        }
        const char* Ab_ = (const char*)La[cur];
        const char* Bb_ = (const char*)Lb[cur];
        bf16x8 af[4], bfr[4];
#pragma unroll
        for (int mi = 0; mi < 4; ++mi)
            af[mi] = *(const bf16x8*)(Ab_ + (wm * 64 + mi * 16 + c) * 64 + ((g * 16) ^ xr));
#pragma unroll
        for (int ni = 0; ni < 4; ++ni)
            bfr[ni] = *(const bf16x8*)(Bb_ + (wn * 64 + ni * 16 + c) * 64 + ((g * 16) ^ xr));
        __builtin_amdgcn_s_setprio(1);
#pragma unroll
        for (int mi = 0; mi < 4; ++mi)
#pragma unroll
            for (int ni = 0; ni < 4; ++ni)
                acc[mi][ni] = MFMA16(af[mi], bfr[ni], acc[mi][ni]);
        __builtin_amdgcn_s_setprio(0);
        ++cur; if (cur == 3) cur = 0;
    }

    if (mat < 2) {
        short* Cb = (mat == 0) ? Oq : Ok;
#pragma unroll
        for (int mi = 0; mi < 4; ++mi)
#pragma unroll
            for (int ni = 0; ni < 4; ++ni) {
                int col = n0m + wn * 64 + ni * 16 + c;
                float bvv = bias[col] * bscl;
#pragma unroll
                for (int r = 0; r < 4; ++r) {
                    int row = m0 + wm * 64 + mi * 16 + g * 4 + r;
                    Cb[(size_t)row * 1024 + col] = (short)f2b(acc[mi][ni][r] + bvv);
                }
            }
    } else {
        // V: write transposed to Vt[bh=b*16+h][hd][s], s-contiguous short4
#pragma unroll
        for (int mi = 0; mi < 4; ++mi)
#pragma unroll
            for (int ni = 0; ni < 4; ++ni) {
                int col = n0m + wn * 64 + ni * 16 + c;  // d index
                int h = col >> 6, hd = col & 63;
                float bvv = bias[col];
                int row0 = m0 + wm * 64 + mi * 16 + g * 4;  // 4 consecutive s
                int b = row0 >> 11, s = row0 & 2047;
                short4 pk;
                pk.x = (short)f2b(acc[mi][ni][0] + bvv);
                pk.y = (short)f2b(acc[mi][ni][1] + bvv);
                pk.z = (short)f2b(acc[mi][ni][2] + bvv);
                pk.w = (short)f2b(acc[mi][ni][3] + bvv);
                *(short4*)(Ovt + ((size_t)((b * 16 + h) * 64 + hd)) * S + s) = pk;
            }
    }
}

// ---------------- out-proj GEMM: 128x128 tile, 4 waves, BK=32, 3-buf pipeline, fp32 out ----------------
// grid (8, 32) = 256 blocks = 1/CU uniform.
__global__ __launch_bounds__(256, 3) void out_gemm(const short* __restrict__ A,
                                                   const short* __restrict__ Bm,
                                                   const float* __restrict__ bias,
                                                   float* __restrict__ C) {
    constexpr int Kd = 1024, N = 1024;
    __shared__ short La[3][128 * 32];
    __shared__ short Lb[3][128 * 32];
    const int n0 = blockIdx.x * 128, m0 = blockIdx.y * 128;
    const int t = threadIdx.x;
    const int w = t >> 6, lane = t & 63;
    const int wm = w >> 1, wn = w & 1;
    const int c = lane & 15, g = lane >> 4;

    f32x4 acc[4][4] = {};

    auto stage = [&](int buf, int k0) {
#pragma unroll
        for (int cc = 0; cc < 2; ++cc) {
            int chunk = cc * 256 + t;
            int row = chunk >> 2, s = chunk & 3;
            int colb = (s * 16) ^ (((row >> 1) & 3) << 4);
            GLD_LDS(A + (size_t)(m0 + row) * Kd + k0 + (colb >> 1), &La[buf][chunk * 8]);
            GLD_LDS(Bm + (size_t)(n0 + row) * Kd + k0 + (colb >> 1), &Lb[buf][chunk * 8]);
        }
    };

    stage(0, 0);
    stage(1, 32);
    const int xr = ((c >> 1) & 3) << 4;

    int cur = 0;
#pragma unroll 1
    for (int ks = 0; ks < 32; ++ks) {
        if (ks < 31) asm volatile("s_waitcnt vmcnt(4)" ::: "memory");
        else         asm volatile("s_waitcnt vmcnt(0)" ::: "memory");
        __builtin_amdgcn_sched_barrier(0);
        __builtin_amdgcn_s_barrier();
        __builtin_amdgcn_sched_barrier(0);
        if (ks + 2 < 32) {
            int nb = cur + 2; if (nb >= 3) nb -= 3;
            stage(nb, (ks + 2) * 32);
        }
        const char* Ab_ = (const char*)La[cur];
        const char* Bb_ = (const char*)Lb[cur];
        bf16x8 af[4], bfr[4];
#pragma unroll
        for (int mi = 0; mi < 4; ++mi)
            af[mi] = *(const bf16x8*)(Ab_ + (wm * 64 + mi * 16 + c) * 64 + ((g * 16) ^ xr));
#pragma unroll
        for (int ni = 0; ni < 4; ++ni)
            bfr[ni] = *(const bf16x8*)(Bb_ + (wn * 64 + ni * 16 + c) * 64 + ((g * 16) ^ xr));
        __builtin_amdgcn_s_setprio(1);
#pragma unroll
        for (int mi = 0; mi < 4; ++mi)
#pragma unroll
            for (int ni = 0; ni < 4; ++ni)
                acc[mi][ni] = MFMA16(af[mi], bfr[ni], acc[mi][ni]);
        __builtin_amdgcn_s_setprio(0);
        ++cur; if (cur == 3) cur = 0;
    }

#pragma unroll
    for (int mi = 0; mi < 4; ++mi)
#pragma unroll
        for (int ni = 0; ni < 4; ++ni) {
            int col = n0 + wn * 64 + ni * 16 + c;
            float bvv = bias[col];
#pragma unroll
            for (int r = 0; r < 4; ++r) {
                int row = m0 + wm * 64 + mi * 16 + g * 4 + r;
                C[(size_t)row * N + col] = acc[mi][ni][r] + bvv;
            }
        }
}

// ---------------- flash attention: fixed-max softmax + 3-buf counted-vmcnt pipeline ----------------
// grid 1024: bh = id&31, qtile = 31 - id>>5 (heavy first). 4 waves, wave w = 16 q-rows.
// One s_barrier per 64-key tile; vmcnt(4) keeps next tile's K/V loads in flight.
__global__ __launch_bounds__(256, 2) void attn_kernel(const short* Q,
                                                      const short* __restrict__ Kg,
                                                      const short* __restrict__ Vt,
                                                      short* O) {
    constexpr int S = 2048, D = 1024;
    constexpr float M2 = 16.0f;
    __shared__ short Ks[3][4096];
    __shared__ short Vs[3][4096];
    __shared__ short Pl[4][1024];
    const int id = blockIdx.x;
    const int bh = id & 31, b = bh >> 4, h = bh & 15;
    const int qtile = 31 - (id >> 5);
    const int t = threadIdx.x;
    const int w = t >> 6, lane = t & 63;
    const int c = lane & 15, g = lane >> 4;
    const int q0 = qtile * 64 + w * 16;

    const short* Qb = Q + (size_t)b * S * D + h * 64;
    const short* Kp = Kg + (size_t)b * S * D + h * 64;
    const short* Vp = Vt + (size_t)bh * 64 * S;

    bf16x8 aq0 = *(const bf16x8*)(Qb + (size_t)(q0 + c) * D + g * 8);
    bf16x8 aq1 = *(const bf16x8*)(Qb + (size_t)(q0 + c) * D + 32 + g * 8);

    f32x4 o[4] = {};
    float l_part[4] = {0.f, 0.f, 0.f, 0.f};
    const int ktmax = qtile + 1;

    auto stageKV = [&](int buf, int kt) {
        int k0 = kt * 64;
#pragma unroll
        for (int cc = 0; cc < 2; ++cc) {
            int row = cc * 32 + (t >> 3);
            int colb = ((t & 7) * 16) ^ ((row & 7) << 4);
            GLD_LDS(Kp + (size_t)(k0 + row) * D + (colb >> 1), &Ks[buf][cc * 2048 + t * 8]);
            GLD_LDS(Vp + (size_t)row * S + k0 + (colb >> 1), &Vs[buf][cc * 2048 + t * 8]);
        }
    };

    stageKV(0, 0);
    if (ktmax > 1) stageKV(1, 1);
    const int swc = (c & 7) << 4;

    int cur = 0;
#pragma unroll 1
    for (int kt = 0; kt < ktmax; ++kt) {
        if (kt + 1 < ktmax) asm volatile("s_waitcnt vmcnt(4)" ::: "memory");
        else                asm volatile("s_waitcnt vmcnt(0)" ::: "memory");
        __builtin_amdgcn_sched_barrier(0);
        __builtin_amdgcn_s_barrier();
        __builtin_amdgcn_sched_barrier(0);
        if (kt + 2 < ktmax) {
            int nb = cur + 2; if (nb >= 3) nb -= 3;
            stageKV(nb, kt + 2);
        }
        const char* KsB = (const char*)Ks[cur];
        const char* VsB = (const char*)Vs[cur];
        const int k0 = kt * 64;

        // QK^T: 64 keys (scores already base-2; scale folded into Q)
        f32x4 sc[4];
#pragma unroll
        for (int nt = 0; nt < 4; ++nt) {
            const char* rb = KsB + (nt * 16 + c) * 128;
            bf16x8 bk0 = *(const bf16x8*)(rb + ((g * 16) ^ swc));
            bf16x8 bk1 = *(const bf16x8*)(rb + ((64 + g * 16) ^ swc));
            f32x4 z = {};
            z = MFMA16(aq0, bk0, z);
            z = MFMA16(aq1, bk1, z);
            sc[nt] = z;
        }
        if (kt == ktmax - 1) {  // only diagonal tile needs masking
#pragma unroll
            for (int nt = 0; nt < 4; ++nt)
#pragma unroll
                for (int r = 0; r < 4; ++r) {
                    int key = k0 + nt * 16 + c;
                    int qr = q0 + g * 4 + r;
                    if (key > qr) sc[nt][r] = -3e38f;
                }
        }
        // P = exp2(sc - M2); per-lane l; P -> per-wave LDS (swizzled)
        char* pw = (char*)&Pl[w][0];
#pragma unroll
        for (int nt = 0; nt < 4; ++nt)
#pragma unroll
            for (int r = 0; r < 4; ++r) {
                float p = __builtin_exp2f(sc[nt][r] - M2);
                l_part[r] += p;
                int prow = g * 4 + r;
                int pb = ((nt * 16 + c) * 2) ^ ((prow & 7) << 4);
                *(short*)(pw + prow * 128 + pb) = (short)f2b(p);
            }
        asm volatile("" ::: "memory");
        // PV
#pragma unroll
        for (int half = 0; half < 2; ++half) {
            bf16x8 pa = *(const bf16x8*)(pw + c * 128 + ((half * 64 + g * 16) ^ swc));
#pragma unroll
            for (int n2 = 0; n2 < 4; ++n2) {
                bf16x8 bv = *(const bf16x8*)(VsB + (n2 * 16 + c) * 128 +
                                             ((half * 64 + g * 16) ^ swc));
                o[n2] = MFMA16(pa, bv, o[n2]);
            }
        }
        ++cur; if (cur == 3) cur = 0;
    }

    // final l reduce across the 16 lanes of each g-group
#pragma unroll
    for (int d = 1; d < 16; d <<= 1)
#pragma unroll
        for (int r = 0; r < 4; ++r) l_part[r] += __shfl_xor(l_part[r], d);

    short* Ob = O + (size_t)b * S * D + h * 64;
#pragma unroll
    for (int r = 0; r < 4; ++r) {
        float inv = 1.0f / l_part[r];
        int row = q0 + g * 4 + r;
#pragma unroll
        for (int n2 = 0; n2 < 4; ++n2)
            Ob[(size_t)row * D + n2 * 16 + c] = (short)f2b(o[n2][r] * inv);
    }
}

extern "C" void kernel_launch(void* const* d_in, const int* in_sizes, int n_in,
                              void* d_out, int out_size, void* d_ws, size_t ws_size,
                              hipStream_t stream) {
    const float* x  = (const float*)d_in[0];
    const float* wq = (const float*)d_in[1];
    const float* bq = (const float*)d_in[2];
    const float* wk = (const float*)d_in[3];
    const float* bk = (const float*)d_in[4];
    const float* wv = (const float*)d_in[5];
    const float* bv = (const float*)d_in[6];
    const float* wo = (const float*)d_in[7];
    const float* bo = (const float*)d_in[8];
    float* out = (float*)d_out;

    char* ws = (char*)d_ws;
    const size_t SZ_X = (size_t)4096 * 1024 * 2;  // 8 MB
    const size_t SZ_W = (size_t)1024 * 1024 * 2;  // 2 MB
    short* xb  = (short*)(ws);
    short* wqb = (short*)(ws + SZ_X);
    short* wkb = (short*)(ws + SZ_X + SZ_W);
    short* wvb = (short*)(ws + SZ_X + 2 * SZ_W);
    short* wob = (short*)(ws + SZ_X + 3 * SZ_W);
    short* Qb  = (short*)(ws + SZ_X + 4 * SZ_W);   // also attn output (safe alias)
    short* Kbuf= (short*)(ws + 2 * SZ_X + 4 * SZ_W);
    short* Vtb = (short*)(ws + 3 * SZ_X + 4 * SZ_W);  // V in [bh][hd][s]
    short* Ab  = Qb;

    cvt_all<<<8192, 256, 0, stream>>>(x, wq, wk, wv, wo, xb, wqb, wkb, wvb, wob);

    qkv_gemm<<<dim3(24, 32), 256, 0, stream>>>(xb, wqb, wkb, wvb, bq, bk, bv, Qb, Kbuf, Vtb);

    attn_kernel<<<1024, 256, 0, stream>>>(Qb, Kbuf, Vtb, Ab);

    out_gemm<<<dim3(8, 32), 256, 0, stream>>>(Ab, wob, bo, out);
}